// Round 1
// baseline (1135.232 us; speedup 1.0000x reference)
//
#include <hip/hip_runtime.h>
#include <stdint.h>

typedef short short8 __attribute__((ext_vector_type(8)));
typedef float f32x4 __attribute__((ext_vector_type(4)));

#define T_TOK 8192
#define HID   2048
#define FFNW  1024
#define NE    8
#define NPAIR (2 * T_TOK)

#define BM  128
#define BN1 64
#define BN2 64
#define BK  32
#define APITCH 40   // 32 + 8 pad (ushort elems) -> 80B row stride, ~2-way banks

__device__ __forceinline__ unsigned short f2bf(float f) {
  unsigned int b = __float_as_uint(f);
  b += 0x7fffu + ((b >> 16) & 1u);   // RNE
  return (unsigned short)(b >> 16);
}

// ---------------- cast f32 -> bf16 (8 elems/thread) ----------------
__global__ __launch_bounds__(256) void k_cast(const float* __restrict__ in,
                                              unsigned short* __restrict__ out,
                                              long n8) {
  long i = (long)blockIdx.x * blockDim.x + threadIdx.x;
  long stride = (long)gridDim.x * blockDim.x;
  for (; i < n8; i += stride) {
    const float4* p = (const float4*)(in + i * 8);
    float4 a = p[0], b = p[1];
    uint4 o;
    o.x = (unsigned)f2bf(a.x) | ((unsigned)f2bf(a.y) << 16);
    o.y = (unsigned)f2bf(a.z) | ((unsigned)f2bf(a.w) << 16);
    o.z = (unsigned)f2bf(b.x) | ((unsigned)f2bf(b.y) << 16);
    o.w = (unsigned)f2bf(b.z) | ((unsigned)f2bf(b.w) << 16);
    ((uint4*)out)[i] = o;
  }
}

// ---------------- zero f32 region ----------------
__global__ __launch_bounds__(256) void k_zero(float4* __restrict__ p, long n4) {
  long i = (long)blockIdx.x * blockDim.x + threadIdx.x;
  long stride = (long)gridDim.x * blockDim.x;
  float4 z; z.x = z.y = z.z = z.w = 0.f;
  for (; i < n4; i += stride) p[i] = z;
}

__global__ void k_init(int* counts) {
  if (threadIdx.x < NE) counts[threadIdx.x] = 0;
}

// ---------------- router: wave per token ----------------
__global__ __launch_bounds__(256) void k_router(const float* __restrict__ x,
                                                const float* __restrict__ gw,
                                                float* __restrict__ logits,
                                                int* __restrict__ sel,
                                                float* __restrict__ cw,
                                                int* __restrict__ counts) {
  int wid = threadIdx.x >> 6, lane = threadIdx.x & 63;
  int t = blockIdx.x * 4 + wid;
  const float4* xr = (const float4*)(x + (size_t)t * HID);
  float acc[NE];
#pragma unroll
  for (int e = 0; e < NE; e++) acc[e] = 0.f;
  for (int i = lane; i < HID / 4; i += 64) {
    float4 xv = xr[i];
#pragma unroll
    for (int e = 0; e < NE; e++) {
      float4 gv = ((const float4*)(gw + (size_t)e * HID))[i];
      acc[e] += xv.x * gv.x + xv.y * gv.y + xv.z * gv.z + xv.w * gv.w;
    }
  }
#pragma unroll
  for (int e = 0; e < NE; e++)
    for (int off = 32; off; off >>= 1) acc[e] += __shfl_down(acc[e], off);
  if (lane == 0) {
    float mx = acc[0];
#pragma unroll
    for (int e = 1; e < NE; e++) mx = fmaxf(mx, acc[e]);
    float p[NE];
#pragma unroll
    for (int e = 0; e < NE; e++) p[e] = expf(acc[e] - mx);
    int i1 = 0; float b1 = p[0];
#pragma unroll
    for (int e = 1; e < NE; e++) if (p[e] > b1) { b1 = p[e]; i1 = e; }
    int i2 = -1; float b2 = -1.f;
#pragma unroll
    for (int e = 0; e < NE; e++) if (e != i1 && p[e] > b2) { b2 = p[e]; i2 = e; }
    float denom = b1 + b2;
#pragma unroll
    for (int e = 0; e < NE; e++) logits[(size_t)t * NE + e] = acc[e];
    sel[2 * t] = i1; sel[2 * t + 1] = i2;
    cw[2 * t] = b1 / denom; cw[2 * t + 1] = b2 / denom;
    atomicAdd(&counts[i1], 1);
    atomicAdd(&counts[i2], 1);
  }
}

__global__ void k_offsets(const int* __restrict__ counts, int* __restrict__ base,
                          int* __restrict__ cursor) {
  if (threadIdx.x == 0 && blockIdx.x == 0) {
    int acc = 0;
    for (int e = 0; e < NE; e++) { base[e] = acc; cursor[e] = acc; acc += counts[e]; }
    base[NE] = acc;
  }
}

__global__ __launch_bounds__(256) void k_scatter(const int* __restrict__ sel,
                                                 const float* __restrict__ cw,
                                                 int* __restrict__ cursor,
                                                 int* __restrict__ tokc,
                                                 float* __restrict__ coefc) {
  int t = blockIdx.x * blockDim.x + threadIdx.x;
  if (t >= T_TOK) return;
#pragma unroll
  for (int k = 0; k < 2; k++) {
    int e = sel[2 * t + k];
    int pos = atomicAdd(&cursor[e], 1);
    tokc[pos] = t;
    coefc[pos] = cw[2 * t + k];
  }
}

// ---------------- GEMM1: act = silu(x@w1^T) * (x@w3^T), gathered rows ----------------
__global__ __launch_bounds__(256) void k_gemm1(const unsigned short* __restrict__ xb,
                                               const unsigned short* __restrict__ w13b,
                                               unsigned short* __restrict__ act,
                                               const int* __restrict__ counts,
                                               const int* __restrict__ base,
                                               const int* __restrict__ tokc) {
  int e = blockIdx.z;
  int cnt = counts[e];
  int m0 = blockIdx.x * BM;
  if (m0 >= cnt) return;
  int n0 = blockIdx.y * BN1;
  int bs = base[e];

  __shared__ unsigned short sA[BM * APITCH];
  __shared__ unsigned short sBg[BN1 * APITCH];
  __shared__ unsigned short sBu[BN1 * APITCH];
  __shared__ int s_tok[BM];

  int tid = threadIdx.x;
  if (tid < BM) {
    int slot = m0 + tid;
    s_tok[tid] = tokc[bs + (slot < cnt ? slot : 0)];
  }
  __syncthreads();

  int lane = tid & 63, wid = tid >> 6;
  int wm = wid * 32;
  int rrow = lane & 15, kq = (lane >> 4) * 8;

  f32x4 accg[2][4], accu[2][4];
#pragma unroll
  for (int mi = 0; mi < 2; mi++)
#pragma unroll
    for (int ni = 0; ni < 4; ni++) {
      accg[mi][ni] = (f32x4)(0.f);
      accu[mi][ni] = (f32x4)(0.f);
    }

  const size_t wbase = (size_t)e * 2 * FFNW * HID;

  for (int k0 = 0; k0 < HID; k0 += BK) {
    // stage A: 128 rows x 32 cols bf16 = 512 16B-chunks
#pragma unroll
    for (int p = 0; p < 2; p++) {
      int idx = p * 256 + tid;
      int row = idx >> 2, kc = idx & 3;
      uint4 v = *(const uint4*)(xb + (size_t)s_tok[row] * HID + k0 + kc * 8);
      *(uint4*)(sA + row * APITCH + kc * 8) = v;
    }
    {
      int row = tid >> 2, kc = tid & 3;
      *(uint4*)(sBg + row * APITCH + kc * 8) =
          *(const uint4*)(w13b + wbase + (size_t)(n0 + row) * HID + k0 + kc * 8);
      *(uint4*)(sBu + row * APITCH + kc * 8) =
          *(const uint4*)(w13b + wbase + (size_t)(FFNW + n0 + row) * HID + k0 + kc * 8);
    }
    __syncthreads();

    short8 a[2], bg[4], bu[4];
#pragma unroll
    for (int mi = 0; mi < 2; mi++)
      a[mi] = *(const short8*)(sA + (wm + mi * 16 + rrow) * APITCH + kq);
#pragma unroll
    for (int ni = 0; ni < 4; ni++) {
      bg[ni] = *(const short8*)(sBg + (ni * 16 + rrow) * APITCH + kq);
      bu[ni] = *(const short8*)(sBu + (ni * 16 + rrow) * APITCH + kq);
    }
#pragma unroll
    for (int mi = 0; mi < 2; mi++)
#pragma unroll
      for (int ni = 0; ni < 4; ni++) {
        accg[mi][ni] = __builtin_amdgcn_mfma_f32_16x16x32_bf16(a[mi], bg[ni], accg[mi][ni], 0, 0, 0);
        accu[mi][ni] = __builtin_amdgcn_mfma_f32_16x16x32_bf16(a[mi], bu[ni], accu[mi][ni], 0, 0, 0);
      }
    __syncthreads();
  }

  int rb = (lane >> 4) * 4;
  int col_l = lane & 15;
#pragma unroll
  for (int mi = 0; mi < 2; mi++)
#pragma unroll
    for (int ni = 0; ni < 4; ni++)
#pragma unroll
      for (int r = 0; r < 4; r++) {
        int m = wm + mi * 16 + rb + r;
        int slot = m0 + m;
        if (slot < cnt) {
          float g = accg[mi][ni][r];
          float u = accu[mi][ni][r];
          float sv = g / (1.f + expf(-g));
          act[(size_t)(bs + slot) * FFNW + n0 + ni * 16 + col_l] = f2bf(sv * u);
        }
      }
}

// ---------------- GEMM2: out[t] += coef * (act @ w2^T) ----------------
__global__ __launch_bounds__(256) void k_gemm2(const unsigned short* __restrict__ act,
                                               const unsigned short* __restrict__ w2b,
                                               float* __restrict__ out,
                                               const int* __restrict__ counts,
                                               const int* __restrict__ base,
                                               const int* __restrict__ tokc,
                                               const float* __restrict__ coefc) {
  int e = blockIdx.z;
  int cnt = counts[e];
  int m0 = blockIdx.x * BM;
  if (m0 >= cnt) return;
  int n0 = blockIdx.y * BN2;
  int bs = base[e];

  __shared__ unsigned short sA[BM * APITCH];
  __shared__ unsigned short sB[BN2 * APITCH];
  __shared__ int s_tok[BM];
  __shared__ float s_cw[BM];

  int tid = threadIdx.x;
  if (tid < BM) {
    int slot = m0 + tid;
    bool v = slot < cnt;
    s_tok[tid] = v ? tokc[bs + slot] : 0;
    s_cw[tid] = v ? coefc[bs + slot] : 0.f;
  }
  __syncthreads();

  int lane = tid & 63, wid = tid >> 6;
  int wm = wid * 32;
  int rrow = lane & 15, kq = (lane >> 4) * 8;

  f32x4 acc[2][4];
#pragma unroll
  for (int mi = 0; mi < 2; mi++)
#pragma unroll
    for (int ni = 0; ni < 4; ni++) acc[mi][ni] = (f32x4)(0.f);

  const size_t w2base = (size_t)e * HID * FFNW;

  for (int k0 = 0; k0 < FFNW; k0 += BK) {
#pragma unroll
    for (int p = 0; p < 2; p++) {
      int idx = p * 256 + tid;
      int row = idx >> 2, kc = idx & 3;
      int slot = m0 + row;
      int aslot = bs + (slot < cnt ? slot : 0);
      uint4 v = *(const uint4*)(act + (size_t)aslot * FFNW + k0 + kc * 8);
      *(uint4*)(sA + row * APITCH + kc * 8) = v;
    }
    {
      int row = tid >> 2, kc = tid & 3;
      *(uint4*)(sB + row * APITCH + kc * 8) =
          *(const uint4*)(w2b + w2base + (size_t)(n0 + row) * FFNW + k0 + kc * 8);
    }
    __syncthreads();

    short8 a[2], b[4];
#pragma unroll
    for (int mi = 0; mi < 2; mi++)
      a[mi] = *(const short8*)(sA + (wm + mi * 16 + rrow) * APITCH + kq);
#pragma unroll
    for (int ni = 0; ni < 4; ni++)
      b[ni] = *(const short8*)(sB + (ni * 16 + rrow) * APITCH + kq);
#pragma unroll
    for (int mi = 0; mi < 2; mi++)
#pragma unroll
      for (int ni = 0; ni < 4; ni++)
        acc[mi][ni] = __builtin_amdgcn_mfma_f32_16x16x32_bf16(a[mi], b[ni], acc[mi][ni], 0, 0, 0);
    __syncthreads();
  }

  int rb = (lane >> 4) * 4;
  int col_l = lane & 15;
#pragma unroll
  for (int mi = 0; mi < 2; mi++)
#pragma unroll
    for (int ni = 0; ni < 4; ni++)
#pragma unroll
      for (int r = 0; r < 4; r++) {
        int m = wm + mi * 16 + rb + r;
        int slot = m0 + m;
        if (slot < cnt) {
          float v = s_cw[m] * acc[mi][ni][r];
          atomicAdd(out + (size_t)s_tok[m] * HID + n0 + ni * 16 + col_l, v);
        }
      }
}

extern "C" void kernel_launch(void* const* d_in, const int* in_sizes, int n_in,
                              void* d_out, int out_size, void* d_ws, size_t ws_size,
                              hipStream_t stream) {
  const float* x   = (const float*)d_in[0];
  const float* gw  = (const float*)d_in[1];
  const float* w13 = (const float*)d_in[2];
  const float* w2  = (const float*)d_in[3];
  float* out = (float*)d_out;
  float* logits = out + (size_t)T_TOK * HID;

  uint8_t* p = (uint8_t*)d_ws;
  unsigned short* xb = (unsigned short*)p;   p += (size_t)T_TOK * HID * 2;
  unsigned short* w13b = (unsigned short*)p; p += (size_t)NE * 2 * FFNW * HID * 2;
  unsigned short* w2b = (unsigned short*)p;  p += (size_t)NE * HID * FFNW * 2;
  unsigned short* act = (unsigned short*)p;  p += (size_t)NPAIR * FFNW * 2;
  int* sel = (int*)p;    p += (size_t)T_TOK * 2 * 4;
  float* cw = (float*)p; p += (size_t)T_TOK * 2 * 4;
  int* tokc = (int*)p;   p += (size_t)NPAIR * 4;
  float* coefc = (float*)p; p += (size_t)NPAIR * 4;
  int* counts = (int*)p; p += 256;
  int* cursor = (int*)p; p += 256;
  int* base = (int*)p;   p += 256;
  if ((size_t)(p - (uint8_t*)d_ws) > ws_size) return;  // ws too small -> clean fail

  k_cast<<<2048, 256, 0, stream>>>(x, xb, (long)T_TOK * HID / 8);
  k_cast<<<2048, 256, 0, stream>>>(w13, w13b, (long)NE * 2 * FFNW * HID / 8);
  k_cast<<<2048, 256, 0, stream>>>(w2, w2b, (long)NE * HID * FFNW / 8);
  k_init<<<1, 64, 0, stream>>>(counts);
  k_router<<<T_TOK / 4, 256, 0, stream>>>(x, gw, logits, sel, cw, counts);
  k_offsets<<<1, 1, 0, stream>>>(counts, base, cursor);
  k_scatter<<<T_TOK / 256, 256, 0, stream>>>(sel, cw, cursor, tokc, coefc);
  k_zero<<<2048, 256, 0, stream>>>((float4*)out, (long)T_TOK * HID / 4);
  k_gemm1<<<dim3(T_TOK / BM, FFNW / BN1, NE), 256, 0, stream>>>(xb, w13b, act, counts, base, tokc);
  k_gemm2<<<dim3(T_TOK / BM, HID / BN2, NE), 256, 0, stream>>>(act, w2b, out, counts, base, tokc, coefc);
}

// Round 2
// 829.902 us; speedup vs baseline: 1.3679x; 1.3679x over previous
//
#include <hip/hip_runtime.h>
#include <stdint.h>

typedef short short8 __attribute__((ext_vector_type(8)));
typedef float f32x4 __attribute__((ext_vector_type(4)));

#define T_TOK 8192
#define HID   2048
#define FFNW  1024
#define NE    8
#define NPAIR (2 * T_TOK)

__device__ __forceinline__ unsigned short f2bf(float f) {
  unsigned int b = __float_as_uint(f);
  b += 0x7fffu + ((b >> 16) & 1u);   // RNE
  return (unsigned short)(b >> 16);
}
__device__ __forceinline__ float bf2f(unsigned short u) {
  return __uint_as_float(((unsigned)u) << 16);
}

#define GLOAD16(gptr, lptr)                                                          \
  __builtin_amdgcn_global_load_lds(                                                  \
      (const __attribute__((address_space(1))) unsigned int*)(gptr),                 \
      (__attribute__((address_space(3))) unsigned int*)(lptr), 16, 0, 0)

// ---------------- cast f32 -> bf16 (8 elems/thread) ----------------
__global__ __launch_bounds__(256) void k_cast(const float* __restrict__ in,
                                              unsigned short* __restrict__ out,
                                              long n8) {
  long i = (long)blockIdx.x * blockDim.x + threadIdx.x;
  long stride = (long)gridDim.x * blockDim.x;
  for (; i < n8; i += stride) {
    const float4* p = (const float4*)(in + i * 8);
    float4 a = p[0], b = p[1];
    uint4 o;
    o.x = (unsigned)f2bf(a.x) | ((unsigned)f2bf(a.y) << 16);
    o.y = (unsigned)f2bf(a.z) | ((unsigned)f2bf(a.w) << 16);
    o.z = (unsigned)f2bf(b.x) | ((unsigned)f2bf(b.y) << 16);
    o.w = (unsigned)f2bf(b.z) | ((unsigned)f2bf(b.w) << 16);
    ((uint4*)out)[i] = o;
  }
}

__global__ void k_init(int* counts) {
  if (threadIdx.x < NE) counts[threadIdx.x] = 0;
}

// ---------------- router: wave per token ----------------
__global__ __launch_bounds__(256) void k_router(const float* __restrict__ x,
                                                const float* __restrict__ gw,
                                                float* __restrict__ logits,
                                                int* __restrict__ sel,
                                                float* __restrict__ cw,
                                                int* __restrict__ counts) {
  int wid = threadIdx.x >> 6, lane = threadIdx.x & 63;
  int t = blockIdx.x * 4 + wid;
  const float4* xr = (const float4*)(x + (size_t)t * HID);
  float acc[NE];
#pragma unroll
  for (int e = 0; e < NE; e++) acc[e] = 0.f;
  for (int i = lane; i < HID / 4; i += 64) {
    float4 xv = xr[i];
#pragma unroll
    for (int e = 0; e < NE; e++) {
      float4 gv = ((const float4*)(gw + (size_t)e * HID))[i];
      acc[e] += xv.x * gv.x + xv.y * gv.y + xv.z * gv.z + xv.w * gv.w;
    }
  }
#pragma unroll
  for (int e = 0; e < NE; e++)
    for (int off = 32; off; off >>= 1) acc[e] += __shfl_down(acc[e], off);
  if (lane == 0) {
    float mx = acc[0];
#pragma unroll
    for (int e = 1; e < NE; e++) mx = fmaxf(mx, acc[e]);
    float p[NE];
#pragma unroll
    for (int e = 0; e < NE; e++) p[e] = expf(acc[e] - mx);
    int i1 = 0; float b1 = p[0];
#pragma unroll
    for (int e = 1; e < NE; e++) if (p[e] > b1) { b1 = p[e]; i1 = e; }
    int i2 = -1; float b2 = -1.f;
#pragma unroll
    for (int e = 0; e < NE; e++) if (e != i1 && p[e] > b2) { b2 = p[e]; i2 = e; }
    float denom = b1 + b2;
#pragma unroll
    for (int e = 0; e < NE; e++) logits[(size_t)t * NE + e] = acc[e];
    sel[2 * t] = i1; sel[2 * t + 1] = i2;
    cw[2 * t] = b1 / denom; cw[2 * t + 1] = b2 / denom;
    atomicAdd(&counts[i1], 1);
    atomicAdd(&counts[i2], 1);
  }
}

__global__ void k_offsets(const int* __restrict__ counts, int* __restrict__ base,
                          int* __restrict__ cursor) {
  if (threadIdx.x == 0 && blockIdx.x == 0) {
    int acc = 0;
    for (int e = 0; e < NE; e++) { base[e] = acc; cursor[e] = acc; acc += counts[e]; }
    base[NE] = acc;
  }
}

__global__ __launch_bounds__(256) void k_scatter(const int* __restrict__ sel,
                                                 int* __restrict__ cursor,
                                                 int* __restrict__ tokc,
                                                 int* __restrict__ inv) {
  int t = blockIdx.x * blockDim.x + threadIdx.x;
  if (t >= T_TOK) return;
#pragma unroll
  for (int k = 0; k < 2; k++) {
    int e = sel[2 * t + k];
    int pos = atomicAdd(&cursor[e], 1);
    tokc[pos] = t;
    inv[2 * t + k] = pos;
  }
}

// ---------------- unified 128x128x64 MFMA GEMM (m97 structure + XOR swizzle) -------
// A rows gathered via s_row (token gather for GEMM1, identity+bs for GEMM2).
// W is [NE][ND][KD] row-major (rows = output cols). Y rows compact by pair slot.
template<bool GATHER, int KD, int ND>
__global__ __launch_bounds__(256) void k_gemm(const unsigned short* __restrict__ A,
                                              const unsigned short* __restrict__ W,
                                              unsigned short* __restrict__ Y,
                                              const int* __restrict__ counts,
                                              const int* __restrict__ base,
                                              const int* __restrict__ tokc) {
  int e = blockIdx.z;
  int cnt = counts[e];
  int m0 = blockIdx.x * 128;
  if (m0 >= cnt) return;
  int n0 = blockIdx.y * 128;
  int bs = base[e];

  __shared__ unsigned short sA[128 * 64];
  __shared__ unsigned short sB[128 * 64];
  __shared__ int s_row[128];

  int tid = threadIdx.x;
  if (tid < 128) {
    int slot = m0 + tid;
    int cl = slot < cnt ? slot : 0;
    s_row[tid] = GATHER ? tokc[bs + cl] : (bs + cl);
  }
  __syncthreads();

  int lane = tid & 63, wid = tid >> 6;
  int l3 = lane >> 3, l7 = lane & 7;
  int cs = l7 ^ l3;  // pre-swizzled 16B-chunk index (inverse of read-side XOR)

  const unsigned short* wb = W + (size_t)e * ND * KD;

  size_t aoff[4], boff[4];
  unsigned ldsoff[4];
#pragma unroll
  for (int i = 0; i < 4; i++) {
    int r = wid * 32 + i * 8 + l3;
    aoff[i] = (size_t)s_row[r] * KD + (size_t)cs * 8;
    boff[i] = (size_t)(n0 + r) * KD + (size_t)cs * 8;
    ldsoff[i] = (wid * 32 + i * 8) * 64;  // ushort index, wave-uniform
  }

  f32x4 acc[4][4];
#pragma unroll
  for (int mi = 0; mi < 4; mi++)
#pragma unroll
    for (int ni = 0; ni < 4; ni++) acc[mi][ni] = (f32x4)(0.f);

  int wr = (wid >> 1) * 64, wc = (wid & 1) * 64;
  int frow = lane & 15, fk = lane >> 4;

  for (int k0 = 0; k0 < KD; k0 += 64) {
#pragma unroll
    for (int i = 0; i < 4; i++) {
      GLOAD16(A + aoff[i] + k0, &sA[ldsoff[i]]);
      GLOAD16(wb + boff[i] + k0, &sB[ldsoff[i]]);
    }
    __syncthreads();  // compiler drains vmcnt before barrier

#pragma unroll
    for (int kk = 0; kk < 2; kk++) {
      int cb = ((fk + kk * 4) ^ l7) * 16;  // swizzled byte-within-row
      short8 af[4], bf[4];
#pragma unroll
      for (int mi = 0; mi < 4; mi++)
        af[mi] = *(const short8*)((const char*)sA + (wr + mi * 16 + frow) * 128 + cb);
#pragma unroll
      for (int ni = 0; ni < 4; ni++)
        bf[ni] = *(const short8*)((const char*)sB + (wc + ni * 16 + frow) * 128 + cb);
#pragma unroll
      for (int mi = 0; mi < 4; mi++)
#pragma unroll
        for (int ni = 0; ni < 4; ni++)
          acc[mi][ni] = __builtin_amdgcn_mfma_f32_16x16x32_bf16(af[mi], bf[ni], acc[mi][ni], 0, 0, 0);
    }
    __syncthreads();
  }

  // epilogue: C/D layout col=lane&15, row=(lane>>4)*4+r (m89)
#pragma unroll
  for (int mi = 0; mi < 4; mi++) {
#pragma unroll
    for (int r = 0; r < 4; r++) {
      int row = wr + mi * 16 + fk * 4 + r;
      int slot = m0 + row;
      if (slot < cnt) {
        unsigned short* yr = Y + (size_t)(bs + slot) * ND + n0 + wc + frow;
#pragma unroll
        for (int ni = 0; ni < 4; ni++) yr[ni * 16] = f2bf(acc[mi][ni][r]);
      }
    }
  }
}

// ---------------- SwiGLU: act = silu(g) * u ----------------
__global__ __launch_bounds__(256) void k_swiglu(const unsigned short* __restrict__ h13,
                                                unsigned short* __restrict__ act) {
  long i = (long)blockIdx.x * 256 + threadIdx.x;  // NPAIR * FFNW / 8 threads
  int p = (int)(i >> 7);                          // FFNW/8 = 128 chunks per pair
  int c = (int)(i & 127);
  const unsigned short* hr = h13 + (size_t)p * (2 * FFNW);
  short8 g8 = *(const short8*)(hr + c * 8);
  short8 u8 = *(const short8*)(hr + FFNW + c * 8);
  short8 o;
#pragma unroll
  for (int j = 0; j < 8; j++) {
    float g = bf2f((unsigned short)g8[j]);
    float u = bf2f((unsigned short)u8[j]);
    float sv = g / (1.f + expf(-g));
    o[j] = (short)f2bf(sv * u);
  }
  *(short8*)(act + (size_t)p * FFNW + c * 8) = o;
}

// ---------------- combine: out[t] = c0*y[p0] + c1*y[p1] ----------------
__global__ __launch_bounds__(256) void k_combine(const unsigned short* __restrict__ y,
                                                 const int* __restrict__ inv,
                                                 const float* __restrict__ cw,
                                                 float* __restrict__ out) {
  long i = (long)blockIdx.x * 256 + threadIdx.x;  // T_TOK * HID / 8 threads
  int t = (int)(i >> 8);                          // HID/8 = 256 chunks per token
  int c = (int)(i & 255);
  int p0 = inv[2 * t], p1 = inv[2 * t + 1];
  float c0 = cw[2 * t], c1 = cw[2 * t + 1];
  short8 y0 = *(const short8*)(y + (size_t)p0 * HID + c * 8);
  short8 y1 = *(const short8*)(y + (size_t)p1 * HID + c * 8);
  float4 o0, o1;
  o0.x = c0 * bf2f((unsigned short)y0[0]) + c1 * bf2f((unsigned short)y1[0]);
  o0.y = c0 * bf2f((unsigned short)y0[1]) + c1 * bf2f((unsigned short)y1[1]);
  o0.z = c0 * bf2f((unsigned short)y0[2]) + c1 * bf2f((unsigned short)y1[2]);
  o0.w = c0 * bf2f((unsigned short)y0[3]) + c1 * bf2f((unsigned short)y1[3]);
  o1.x = c0 * bf2f((unsigned short)y0[4]) + c1 * bf2f((unsigned short)y1[4]);
  o1.y = c0 * bf2f((unsigned short)y0[5]) + c1 * bf2f((unsigned short)y1[5]);
  o1.z = c0 * bf2f((unsigned short)y0[6]) + c1 * bf2f((unsigned short)y1[6]);
  o1.w = c0 * bf2f((unsigned short)y0[7]) + c1 * bf2f((unsigned short)y1[7]);
  float4* op = (float4*)(out + (size_t)t * HID + c * 8);
  op[0] = o0;
  op[1] = o1;
}

extern "C" void kernel_launch(void* const* d_in, const int* in_sizes, int n_in,
                              void* d_out, int out_size, void* d_ws, size_t ws_size,
                              hipStream_t stream) {
  const float* x   = (const float*)d_in[0];
  const float* gw  = (const float*)d_in[1];
  const float* w13 = (const float*)d_in[2];
  const float* w2  = (const float*)d_in[3];
  float* out = (float*)d_out;
  float* logits = out + (size_t)T_TOK * HID;

  uint8_t* p = (uint8_t*)d_ws;
  unsigned short* xb   = (unsigned short*)p; p += (size_t)T_TOK * HID * 2;
  unsigned short* w13b = (unsigned short*)p; p += (size_t)NE * 2 * FFNW * HID * 2;
  unsigned short* w2b  = (unsigned short*)p; p += (size_t)NE * HID * FFNW * 2;
  unsigned short* act  = (unsigned short*)p; p += (size_t)NPAIR * FFNW * 2;
  unsigned short* h13  = (unsigned short*)p; p += (size_t)NPAIR * 2 * FFNW * 2;
  unsigned short* y    = h13;  // y aliases h13 (h13 dead after swiglu; both 64MB)
  int* sel  = (int*)p;   p += (size_t)T_TOK * 2 * 4;
  float* cw = (float*)p; p += (size_t)T_TOK * 2 * 4;
  int* tokc = (int*)p;   p += (size_t)NPAIR * 4;
  int* inv  = (int*)p;   p += (size_t)NPAIR * 4;
  int* counts = (int*)p; p += 256;
  int* cursor = (int*)p; p += 256;
  int* base   = (int*)p; p += 256;
  if ((size_t)(p - (uint8_t*)d_ws) > ws_size) return;  // ws too small -> clean fail

  k_cast<<<2048, 256, 0, stream>>>(x, xb, (long)T_TOK * HID / 8);
  k_cast<<<2048, 256, 0, stream>>>(w13, w13b, (long)NE * 2 * FFNW * HID / 8);
  k_cast<<<2048, 256, 0, stream>>>(w2, w2b, (long)NE * HID * FFNW / 8);
  k_init<<<1, 64, 0, stream>>>(counts);
  k_router<<<T_TOK / 4, 256, 0, stream>>>(x, gw, logits, sel, cw, counts);
  k_offsets<<<1, 1, 0, stream>>>(counts, base, cursor);
  k_scatter<<<T_TOK / 256, 256, 0, stream>>>(sel, cursor, tokc, inv);

  // GEMM1: h13[pair][2F] = x_gathered @ w13[e]^T
  k_gemm<true, HID, 2 * FFNW><<<dim3(T_TOK / 128, (2 * FFNW) / 128, NE), 256, 0, stream>>>(
      xb, w13b, h13, counts, base, tokc);
  // SwiGLU
  k_swiglu<<<(int)((long)NPAIR * FFNW / 8 / 256), 256, 0, stream>>>(h13, act);
  // GEMM2: y[pair][H] = act @ w2[e]^T
  k_gemm<false, FFNW, HID><<<dim3(T_TOK / 128, HID / 128, NE), 256, 0, stream>>>(
      act, w2b, y, counts, base, tokc);
  // combine into out
  k_combine<<<(int)((long)T_TOK * HID / 8 / 256), 256, 0, stream>>>(y, inv, cw, out);
}